// Round 16
// baseline (140.343 us; speedup 1.0000x reference)
//
#include <hip/hip_runtime.h>

// NCC loss: five 9x9x9 box sums over (2,1,160,160,160) fp32 volumes, fused.
// Separable box filter; block owns a 32x32 (h,w) tile, streams 32 outputs
// along D. D-window in registers (ring[9][5], compile-time slot index).
//
// R16 == R15 resubmitted (R15 died on container acquisition -- no compile/
// pytest/timing output; kernel never ran. R2->R3, R10/R11->R12 precedent.)
// R15 = R14 (70us) + single barrier per slice + float4 staging.
// R14 accounting: 4200 cyc/slice = ~3300 LDS-issue + ~900 barrier drains
// (2 barriers). Changes:
//  - rs double-buffered on step parity -> barrier2 removed. Hazards: B(k+1)
//    writes rs[p^1] vs C(k) reads rs[p] (disjoint); B(k+2) rewrites rs[p]
//    only after barrier(k+1), which every thread passes after its C(k).
//    sH dbuf hazards unchanged (stage(k)->B(k+1) ordered by barrier(k)).
//  - staging via float4: halo = 48 cols starting w0-8 (w0=32bx -> 16B-
//    aligned; 160%4==0 -> no float4 straddles the edge, validity is
//    per-float4). 960 threads x 1 float4 x {I,J}: 15 b128 LDS writes vs
//    50 b32; global 15 wave-loads vs 50. Phase-B tap base shifts +4 (even,
//    float2 alignment kept).
//  - unchanged: sliding 2-col phase B (640t, 5xfloat2/array), half-split
//    phase C with __builtin_amdgcn_permlane32_swap (validated R14),
//    D-ring, fused finalize. 1 block/CU structural (occupancy knob dead).
// Model: ~3190 LDS + 450 barrier ~= 3650 cyc/slice -> ~60us.
// d_ws: [0:8) double accumulator, [8:12) unsigned completion counter.

#define NB   2
#define NDIM 160
#define TILE 32
#define RE   40      // TILE + 8 halo rows
#define F4W  12      // float4s per halo row (48 cols: w0-8 .. w0+39)
#define DCHUNK 32
#define NDCHUNK (NDIM / DCHUNK)   // 5
#define NSLICE (DCHUNK + 8)       // 40 real slices per block
#define NBLK ((NDIM/TILE)*(NDIM/TILE)*NB*NDCHUNK)   // 250
#define NTHR 1024
#define SLICE_SZ (NDIM * NDIM)

__device__ __forceinline__ float both_halves_sum(float a) {
    // own-half partial + partner-half partial, in every lane.
#if __has_builtin(__builtin_amdgcn_permlane32_swap)
    typedef int v2i __attribute__((ext_vector_type(2)));
    v2i r = __builtin_amdgcn_permlane32_swap(__float_as_int(a),
                                             __float_as_int(a), false, false);
    return __int_as_float(r[0]) + __int_as_float(r[1]);
#else
    return a + __shfl_xor(a, 32, 64);
#endif
}

__global__ __launch_bounds__(NTHR)
void ncc_main(const float* __restrict__ I, const float* __restrict__ J,
              double* __restrict__ out_acc, unsigned int* __restrict__ out_cnt,
              float* __restrict__ out) {
    const int t  = threadIdx.x;
    const int tx = t & 31;
    const int ty = t >> 5;
    const int half = ty & 1;
    const int w0 = blockIdx.x * TILE;
    const int h0 = blockIdx.y * TILE;
    const int b  = blockIdx.z / NDCHUNK;
    const int d0 = (blockIdx.z % NDCHUNK) * DCHUNK;

    const float* Ib = I + (size_t)b * NDIM * SLICE_SZ;
    const float* Jb = J + (size_t)b * NDIM * SLICE_SZ;

    // Halo: [buf][I/J][row][f4], 48 cols/row. Row sums: dbuf on step parity.
    __shared__ float4 sH[2][2][RE][F4W];
    __shared__ float4 rs4[2][RE][TILE + 1];   // {I, J, I2, J2}
    __shared__ float  rss[2][RE][TILE + 1];   // IJ
    __shared__ double wsum[NTHR / 64];

    // Staging map: threads 0..959 move one float4 per array-slice.
    const int sa   = (t / 480) & 1;          // 0=I, 1=J (valid for t<960)
    const int item = t - (t / 480) * 480;    // 0..479
    const int sr   = item / F4W;             // halo row 0..39
    const int sf   = item - sr * F4W;        // float4 idx 0..11
    const int sgr  = h0 - 4 + sr;            // global row
    const int sgc  = w0 - 8 + 4 * sf;        // global col (16B-aligned)
    const bool sval = (t < 960) && ((unsigned)sgr < NDIM) &&
                      ((unsigned)sgc < NDIM) && (sgc + 3 < NDIM);
    const int sgoff = sgr * NDIM + sgc;

    // Phase-B map: threads t<640 (waves 0-9), 2 output cols each.
    const int br  = t >> 4;                  // halo row 0..39
    const int bw0 = (t & 15) * 2;            // first output col (even)
    // Phase-C map: wave w=ty>>1 owns rows (2w,2w+1); window split 5/5.
    const int rb = (ty & ~1) + half * 5;     // my half's 5-tap base
    const int re = (ty & ~1) + (half ? 0 : 9); // edge row to subtract

    // D-window ring in REGISTERS: ring[j][c], j indexed by constants only.
    float ring[9][5];
#pragma unroll
    for (int k = 0; k < 9; ++k)
#pragma unroll
        for (int c = 0; c < 5; ++c) ring[k][c] = 0.0f;

    float acc[5] = {0.f, 0.f, 0.f, 0.f, 0.f};
    double csum = 0.0;
    const float inv_win = 1.0f / 729.0f;
    int bi = 0;   // buffer/parity index == step & 1

    // Prologue: stage slice dz0 = d0-4 into buf 0 if valid.
    {
        const int dz0 = d0 - 4;
        if ((unsigned)dz0 < NDIM && t < 960) {
            const float* base = (sa ? Jb : Ib) + (size_t)dz0 * SLICE_SZ;
            float4 v = make_float4(0.f, 0.f, 0.f, 0.f);
            if (sval) v = *reinterpret_cast<const float4*>(base + sgoff);
            sH[0][sa][sr][sf] = v;
        }
        __syncthreads();
    }

    // 45 steps (40 real + 5 dummy so step%9 == j exactly); slice dz = d0-4+step.
    // acc = box-sum over slices [dz-8, dz]; output d = dz-4 for steps 8..39.
    for (int o = 0; o < 5; ++o) {
#pragma unroll
        for (int j = 0; j < 9; ++j) {
            const int step = o * 9 + j;
            const int dz = d0 - 4 + step;
            float s[5] = {0.f, 0.f, 0.f, 0.f, 0.f};
            if (step < NSLICE) {                       // block-uniform
                // Prefetch next slice (one float4 per thread, t<960).
                const int dzn = dz + 1;
                const bool pf = (step + 1 < NSLICE) && ((unsigned)dzn < NDIM);
                float4 pv = make_float4(0.f, 0.f, 0.f, 0.f);
                if (pf && sval) {
                    const float* base = (sa ? Jb : Ib) + (size_t)dzn * SLICE_SZ;
                    pv = *reinterpret_cast<const float4*>(base + sgoff);
                }
                if ((unsigned)dz < NDIM && t < 640) {  // wave-uniform
                    // Phase B: sliding 9-tap row sums, 2 output cols/thread.
                    // Output col c taps halo cols c+4..c+12; pair -> 10
                    // floats at even base = 5 aligned float2 per array.
                    const float* rowI = (const float*)sH[bi][0][br];
                    const float* rowJ = (const float*)sH[bi][1][br];
                    const float2* pI = (const float2*)(rowI + bw0 + 4);
                    const float2* pJ = (const float2*)(rowJ + bw0 + 4);
                    float2 iA = pI[0], iB = pI[1], iC = pI[2], iD = pI[3], iE = pI[4];
                    float2 jA = pJ[0], jB = pJ[1], jC = pJ[2], jD = pJ[3], jE = pJ[4];
                    float aI  = iA.x + iA.y + iB.x + iB.y + iC.x + iC.y
                              + iD.x + iD.y + iE.x;
                    float aJ  = jA.x + jA.y + jB.x + jB.y + jC.x + jC.y
                              + jD.x + jD.y + jE.x;
                    float aI2 = iA.x*iA.x + iA.y*iA.y + iB.x*iB.x + iB.y*iB.y
                              + iC.x*iC.x + iC.y*iC.y + iD.x*iD.x + iD.y*iD.y
                              + iE.x*iE.x;
                    float aJ2 = jA.x*jA.x + jA.y*jA.y + jB.x*jB.x + jB.y*jB.y
                              + jC.x*jC.x + jC.y*jC.y + jD.x*jD.x + jD.y*jD.y
                              + jE.x*jE.x;
                    float aIJ = iA.x*jA.x + iA.y*jA.y + iB.x*jB.x + iB.y*jB.y
                              + iC.x*jC.x + iC.y*jC.y + iD.x*jD.x + iD.y*jD.y
                              + iE.x*jE.x;
                    rs4[bi][br][bw0] = make_float4(aI, aJ, aI2, aJ2);
                    rss[bi][br][bw0] = aIJ;
                    aI  += iE.y - iA.x;
                    aJ  += jE.y - jA.x;
                    aI2 += iE.y*iE.y - iA.x*iA.x;
                    aJ2 += jE.y*jE.y - jA.x*jA.x;
                    aIJ += iE.y*jE.y - iA.x*jA.x;
                    rs4[bi][br][bw0 + 1] = make_float4(aI, aJ, aI2, aJ2);
                    rss[bi][br][bw0 + 1] = aIJ;
                }
                // Stage prefetched slice into the OTHER halo buffer (its
                // last readers finished before the previous barrier).
                if (pf && t < 960) sH[bi ^ 1][sa][sr][sf] = pv;
                __syncthreads();   // rs[bi] ready; stage done. (only barrier)
                if ((unsigned)dz < NDIM) {
                    // Phase C: 9-tap column sums via half-wave 5/5 split.
                    // both_halves_sum(a) = 10-row sum (2w..2w+9) in every
                    // lane; subtract the directly-read edge row.
                    // Runs concurrently with next step's B (rs[bi^1]) --
                    // disjoint buffers, no second barrier needed.
                    float a0 = 0.f, a1 = 0.f, a2 = 0.f, a3 = 0.f, a4 = 0.f;
#pragma unroll
                    for (int k = 0; k < 5; ++k) {
                        float4 v = rs4[bi][rb + k][tx];
                        a0 += v.x; a1 += v.y; a2 += v.z; a3 += v.w;
                        a4 += rss[bi][rb + k][tx];
                    }
                    float4 ev = rs4[bi][re][tx];
                    float  es = rss[bi][re][tx];
                    s[0] = both_halves_sum(a0) - ev.x;
                    s[1] = both_halves_sum(a1) - ev.y;
                    s[2] = both_halves_sum(a2) - ev.z;
                    s[3] = both_halves_sum(a3) - ev.w;
                    s[4] = both_halves_sum(a4) - es;
                }
                bi ^= 1;
            }
            // Slide the D-window (constant slot j -> pure registers)
#pragma unroll
            for (int c = 0; c < 5; ++c) {
                acc[c] += s[c] - ring[j][c];
                ring[j][c] = s[c];
            }
            if (step >= 8 && step < 8 + DCHUNK) {
                float Is = acc[0], Js = acc[1];
                float I2 = acc[2], J2 = acc[3], IJ = acc[4];
                float cross = IJ - Is * Js * inv_win;
                float Ivar  = I2 - Is * Is * inv_win;
                float Jvar  = J2 - Js * Js * inv_win;
                float cc = cross * cross / (Ivar * Jvar + 1e-5f);
                csum += (double)cc;
            }
        }
    }

    // Block reduction: wave shuffle, then cross-wave via LDS (16 waves).
#pragma unroll
    for (int off = 32; off > 0; off >>= 1)
        csum += __shfl_down(csum, off, 64);
    if ((t & 63) == 0) wsum[t >> 6] = csum;
    __syncthreads();
    if (t == 0) {
        double total = 0.0;
#pragma unroll
        for (int wv = 0; wv < NTHR / 64; ++wv) total += wsum[wv];
        atomicAdd(out_acc, total);
        __threadfence();
        unsigned int old = atomicAdd(out_cnt, 1u);
        if (old == NBLK - 1) {
            // All other blocks' acc adds are ordered before their counter
            // increments (threadfence); atomic read returns the full total.
            double fin = atomicAdd(out_acc, 0.0);
            out[0] = (float)(-fin / 8192000.0);
        }
    }
}

extern "C" void kernel_launch(void* const* d_in, const int* in_sizes, int n_in,
                              void* d_out, int out_size, void* d_ws, size_t ws_size,
                              hipStream_t stream) {
    const float* I = (const float*)d_in[0];   // y_true
    const float* J = (const float*)d_in[1];   // y_pred
    double* acc = (double*)d_ws;
    unsigned int* cnt = (unsigned int*)((char*)d_ws + 8);

    hipMemsetAsync(d_ws, 0, 16, stream);

    dim3 grid(NDIM / TILE, NDIM / TILE, NB * NDCHUNK);  // 5 x 5 x 10
    ncc_main<<<grid, NTHR, 0, stream>>>(I, J, acc, cnt, (float*)d_out);
}

// Round 17
// 137.229 us; speedup vs baseline: 1.0227x; 1.0227x over previous
//
#include <hip/hip_runtime.h>

// NCC loss: five 9x9x9 box sums over (2,1,160,160,160) fp32 volumes, fused.
// Separable box filter; block owns a 32x32 (h,w) tile, streams 32 outputs
// along D. D-window in registers (ring[9][5], compile-time slot index).
//
// R17 = R16 (66us) + phase-B reads b64 -> b128 via 4-output col groups.
// R16 accounting (model within 8% of measured): per-slice LDS cyc =
// stage 180 + B-reads 800 + B-writes 356 + C 1709 + barrier 450.
// This round: B-reads only. 320 threads (waves 0-4), 4 adjacent output
// cols each; taps = halo cols bg+4..bg+15 (12 floats, 16B-aligned since
// bg%4==0) = 3 float4 reads/array. 100 b64 -> 30 b128 per slice (-440cyc);
// B VALU 1100 -> ~780 (one 9-tap init + 3 slides per group).
// Rejected this round: 2-output phase C (needs 2nd 45-reg D-ring -> ~140
// VGPR; 16-wave block with VGPR>128 cannot launch); rss transpose (b64
// issue cost ~= b32, nets ~0).
// Everything else identical to R16: single barrier/slice (rs dbuf on step
// parity), float4 staging (t<960), half-split phase C with
// __builtin_amdgcn_permlane32_swap (validated R14/R16), D-ring, fused
// finalize. 1 block/CU structural.
// Model: 3055 cyc/slice x1.08 ~= 55us.
// d_ws: [0:8) double accumulator, [8:12) unsigned completion counter.

#define NB   2
#define NDIM 160
#define TILE 32
#define RE   40      // TILE + 8 halo rows
#define F4W  12      // float4s per halo row (48 cols: w0-8 .. w0+39)
#define DCHUNK 32
#define NDCHUNK (NDIM / DCHUNK)   // 5
#define NSLICE (DCHUNK + 8)       // 40 real slices per block
#define NBLK ((NDIM/TILE)*(NDIM/TILE)*NB*NDCHUNK)   // 250
#define NTHR 1024
#define SLICE_SZ (NDIM * NDIM)

__device__ __forceinline__ float both_halves_sum(float a) {
    // own-half partial + partner-half partial, in every lane.
#if __has_builtin(__builtin_amdgcn_permlane32_swap)
    typedef int v2i __attribute__((ext_vector_type(2)));
    v2i r = __builtin_amdgcn_permlane32_swap(__float_as_int(a),
                                             __float_as_int(a), false, false);
    return __int_as_float(r[0]) + __int_as_float(r[1]);
#else
    return a + __shfl_xor(a, 32, 64);
#endif
}

__global__ __launch_bounds__(NTHR)
void ncc_main(const float* __restrict__ I, const float* __restrict__ J,
              double* __restrict__ out_acc, unsigned int* __restrict__ out_cnt,
              float* __restrict__ out) {
    const int t  = threadIdx.x;
    const int tx = t & 31;
    const int ty = t >> 5;
    const int half = ty & 1;
    const int w0 = blockIdx.x * TILE;
    const int h0 = blockIdx.y * TILE;
    const int b  = blockIdx.z / NDCHUNK;
    const int d0 = (blockIdx.z % NDCHUNK) * DCHUNK;

    const float* Ib = I + (size_t)b * NDIM * SLICE_SZ;
    const float* Jb = J + (size_t)b * NDIM * SLICE_SZ;

    // Halo: [buf][I/J][row][f4], 48 cols/row. Row sums: dbuf on step parity.
    __shared__ float4 sH[2][2][RE][F4W];
    __shared__ float4 rs4[2][RE][TILE + 1];   // {I, J, I2, J2}
    __shared__ float  rss[2][RE][TILE + 1];   // IJ
    __shared__ double wsum[NTHR / 64];

    // Staging map: threads 0..959 move one float4 per array-slice.
    const int sa   = (t / 480) & 1;          // 0=I, 1=J (valid for t<960)
    const int item = t - (t / 480) * 480;    // 0..479
    const int sr   = item / F4W;             // halo row 0..39
    const int sf   = item - sr * F4W;        // float4 idx 0..11
    const int sgr  = h0 - 4 + sr;            // global row
    const int sgc  = w0 - 8 + 4 * sf;        // global col (16B-aligned)
    const bool sval = (t < 960) && ((unsigned)sgr < NDIM) &&
                      ((unsigned)sgc < NDIM) && (sgc + 3 < NDIM);
    const int sgoff = sgr * NDIM + sgc;

    // Phase-B map: threads t<320 (waves 0-4), 4 output cols each.
    const int br = t >> 3;                   // halo row 0..39
    const int bg = (t & 7) * 4;              // first output col (0,4,..,28)
    const int f0 = (bg >> 2) + 1;            // first tap float4 (col bg+4)
    // Phase-C map: wave w=ty>>1 owns rows (2w,2w+1); window split 5/5.
    const int rb = (ty & ~1) + half * 5;     // my half's 5-tap base
    const int re = (ty & ~1) + (half ? 0 : 9); // edge row to subtract

    // D-window ring in REGISTERS: ring[j][c], j indexed by constants only.
    float ring[9][5];
#pragma unroll
    for (int k = 0; k < 9; ++k)
#pragma unroll
        for (int c = 0; c < 5; ++c) ring[k][c] = 0.0f;

    float acc[5] = {0.f, 0.f, 0.f, 0.f, 0.f};
    double csum = 0.0;
    const float inv_win = 1.0f / 729.0f;
    int bi = 0;   // buffer/parity index == step & 1

    // Prologue: stage slice dz0 = d0-4 into buf 0 if valid.
    {
        const int dz0 = d0 - 4;
        if ((unsigned)dz0 < NDIM && t < 960) {
            const float* base = (sa ? Jb : Ib) + (size_t)dz0 * SLICE_SZ;
            float4 v = make_float4(0.f, 0.f, 0.f, 0.f);
            if (sval) v = *reinterpret_cast<const float4*>(base + sgoff);
            sH[0][sa][sr][sf] = v;
        }
        __syncthreads();
    }

    // 45 steps (40 real + 5 dummy so step%9 == j exactly); slice dz = d0-4+step.
    // acc = box-sum over slices [dz-8, dz]; output d = dz-4 for steps 8..39.
    for (int o = 0; o < 5; ++o) {
#pragma unroll
        for (int j = 0; j < 9; ++j) {
            const int step = o * 9 + j;
            const int dz = d0 - 4 + step;
            float s[5] = {0.f, 0.f, 0.f, 0.f, 0.f};
            if (step < NSLICE) {                       // block-uniform
                // Prefetch next slice (one float4 per thread, t<960).
                const int dzn = dz + 1;
                const bool pf = (step + 1 < NSLICE) && ((unsigned)dzn < NDIM);
                float4 pv = make_float4(0.f, 0.f, 0.f, 0.f);
                if (pf && sval) {
                    const float* base = (sa ? Jb : Ib) + (size_t)dzn * SLICE_SZ;
                    pv = *reinterpret_cast<const float4*>(base + sgoff);
                }
                if ((unsigned)dz < NDIM && t < 320) {  // wave-uniform
                    // Phase B: sliding 9-tap row sums, 4 output cols/thread.
                    // Taps for cols bg..bg+3 = halo cols bg+4..bg+15:
                    // 3 aligned float4 loads per array.
                    const float4* rowI = sH[bi][0][br];
                    const float4* rowJ = sH[bi][1][br];
                    float4 iA = rowI[f0], iB = rowI[f0+1], iC = rowI[f0+2];
                    float4 jA = rowJ[f0], jB = rowJ[f0+1], jC = rowJ[f0+2];
                    float vi[12] = {iA.x, iA.y, iA.z, iA.w,
                                    iB.x, iB.y, iB.z, iB.w,
                                    iC.x, iC.y, iC.z, iC.w};
                    float vj[12] = {jA.x, jA.y, jA.z, jA.w,
                                    jB.x, jB.y, jB.z, jB.w,
                                    jC.x, jC.y, jC.z, jC.w};
                    // col bg: taps 0..8
                    float aI = 0.f, aJ = 0.f, aI2 = 0.f, aJ2 = 0.f, aIJ = 0.f;
#pragma unroll
                    for (int k = 0; k < 9; ++k) {
                        aI  += vi[k];          aJ  += vj[k];
                        aI2 += vi[k] * vi[k];  aJ2 += vj[k] * vj[k];
                        aIJ += vi[k] * vj[k];
                    }
                    rs4[bi][br][bg] = make_float4(aI, aJ, aI2, aJ2);
                    rss[bi][br][bg] = aIJ;
                    // cols bg+1..bg+3: slide (+tap i+8, -tap i-1)
#pragma unroll
                    for (int i = 1; i < 4; ++i) {
                        float nI = vi[i + 8], nJ = vj[i + 8];
                        float oI = vi[i - 1], oJ = vj[i - 1];
                        aI  += nI - oI;
                        aJ  += nJ - oJ;
                        aI2 += nI * nI - oI * oI;
                        aJ2 += nJ * nJ - oJ * oJ;
                        aIJ += nI * nJ - oI * oJ;
                        rs4[bi][br][bg + i] = make_float4(aI, aJ, aI2, aJ2);
                        rss[bi][br][bg + i] = aIJ;
                    }
                }
                // Stage prefetched slice into the OTHER halo buffer (its
                // last readers finished before the previous barrier).
                if (pf && t < 960) sH[bi ^ 1][sa][sr][sf] = pv;
                __syncthreads();   // rs[bi] ready; stage done. (only barrier)
                if ((unsigned)dz < NDIM) {
                    // Phase C: 9-tap column sums via half-wave 5/5 split.
                    // both_halves_sum(a) = 10-row sum (2w..2w+9) in every
                    // lane; subtract the directly-read edge row.
                    // Runs concurrently with next step's B (rs[bi^1]) --
                    // disjoint buffers, no second barrier needed.
                    float a0 = 0.f, a1 = 0.f, a2 = 0.f, a3 = 0.f, a4 = 0.f;
#pragma unroll
                    for (int k = 0; k < 5; ++k) {
                        float4 v = rs4[bi][rb + k][tx];
                        a0 += v.x; a1 += v.y; a2 += v.z; a3 += v.w;
                        a4 += rss[bi][rb + k][tx];
                    }
                    float4 ev = rs4[bi][re][tx];
                    float  es = rss[bi][re][tx];
                    s[0] = both_halves_sum(a0) - ev.x;
                    s[1] = both_halves_sum(a1) - ev.y;
                    s[2] = both_halves_sum(a2) - ev.z;
                    s[3] = both_halves_sum(a3) - ev.w;
                    s[4] = both_halves_sum(a4) - es;
                }
                bi ^= 1;
            }
            // Slide the D-window (constant slot j -> pure registers)
#pragma unroll
            for (int c = 0; c < 5; ++c) {
                acc[c] += s[c] - ring[j][c];
                ring[j][c] = s[c];
            }
            if (step >= 8 && step < 8 + DCHUNK) {
                float Is = acc[0], Js = acc[1];
                float I2 = acc[2], J2 = acc[3], IJ = acc[4];
                float cross = IJ - Is * Js * inv_win;
                float Ivar  = I2 - Is * Is * inv_win;
                float Jvar  = J2 - Js * Js * inv_win;
                float cc = cross * cross / (Ivar * Jvar + 1e-5f);
                csum += (double)cc;
            }
        }
    }

    // Block reduction: wave shuffle, then cross-wave via LDS (16 waves).
#pragma unroll
    for (int off = 32; off > 0; off >>= 1)
        csum += __shfl_down(csum, off, 64);
    if ((t & 63) == 0) wsum[t >> 6] = csum;
    __syncthreads();
    if (t == 0) {
        double total = 0.0;
#pragma unroll
        for (int wv = 0; wv < NTHR / 64; ++wv) total += wsum[wv];
        atomicAdd(out_acc, total);
        __threadfence();
        unsigned int old = atomicAdd(out_cnt, 1u);
        if (old == NBLK - 1) {
            // All other blocks' acc adds are ordered before their counter
            // increments (threadfence); atomic read returns the full total.
            double fin = atomicAdd(out_acc, 0.0);
            out[0] = (float)(-fin / 8192000.0);
        }
    }
}

extern "C" void kernel_launch(void* const* d_in, const int* in_sizes, int n_in,
                              void* d_out, int out_size, void* d_ws, size_t ws_size,
                              hipStream_t stream) {
    const float* I = (const float*)d_in[0];   // y_true
    const float* J = (const float*)d_in[1];   // y_pred
    double* acc = (double*)d_ws;
    unsigned int* cnt = (unsigned int*)((char*)d_ws + 8);

    hipMemsetAsync(d_ws, 0, 16, stream);

    dim3 grid(NDIM / TILE, NDIM / TILE, NB * NDCHUNK);  // 5 x 5 x 10
    ncc_main<<<grid, NTHR, 0, stream>>>(I, J, acc, cnt, (float*)d_out);
}